// Round 1
// baseline (199.811 us; speedup 1.0000x reference)
//
#include <hip/hip_runtime.h>

#define IH 4096
#define IW 4096
#define KH 16
#define KW 16
#define OH 4081
#define OW 4081

#define TILE 64        // 64x64 output tile per block
#define LROWS 79       // TILE + KH - 1
#define LCHUNKS 20     // 80 floats per LDS row = 20 float4 chunks
#define LSTR 80        // LDS row stride in floats

__global__ __launch_bounds__(256, 4)
void conv16_kernel(const float* __restrict__ x,
                   const float* __restrict__ wgt,
                   const float* __restrict__ bias,
                   float* __restrict__ out) {
    __shared__ float tile[LROWS * LSTR];

    const int t  = threadIdx.x;
    const int tx = t & 7;    // 0..7  -> 8 cols each = 64 cols
    const int ty = t >> 3;   // 0..31 -> 2 rows each = 64 rows
    const int gx0 = blockIdx.x * TILE;
    const int gy0 = blockIdx.y * TILE;

    // ---- stage 79x80 input tile into LDS (float4 chunks, bank-swizzled) ----
    for (int idx = t; idx < LROWS * LCHUNKS; idx += 256) {
        const int row = idx / LCHUNKS;
        const int c   = idx - row * LCHUNKS;
        const int gy  = gy0 + row;
        const int gxc = gx0 + c * 4;
        float4 q = make_float4(0.f, 0.f, 0.f, 0.f);
        if (gy < IH && gxc < IW) {
            q = *reinterpret_cast<const float4*>(x + (size_t)gy * IW + gxc);
        }
        const int cs = c ^ ((row >> 1) & 1);   // bank swizzle
        *reinterpret_cast<float4*>(&tile[row * LSTR + cs * 4]) = q;
    }
    __syncthreads();

    float acc0[8], acc1[8];
#pragma unroll
    for (int c = 0; c < 8; ++c) { acc0[c] = 0.f; acc1[c] = 0.f; }

    float A[24], B[24];
    const int or0 = ty * 2;   // block-local output row of this thread

    // load 24-float window (cols tx*8 .. tx*8+23) of LDS row `row`
    auto load_win = [&](float* Wd, int row) {
        const int w = (row >> 1) & 1;
        const float* rbase = &tile[row * LSTR];
#pragma unroll
        for (int m = 0; m < 6; ++m) {
            const int chunk = (2 * tx + m) ^ w;
            const float4 q = *reinterpret_cast<const float4*>(rbase + chunk * 4);
            Wd[4 * m + 0] = q.x; Wd[4 * m + 1] = q.y;
            Wd[4 * m + 2] = q.z; Wd[4 * m + 3] = q.w;
        }
    };

    // one tap-row u: R0 feeds output row or0, R1 feeds or0+1
    auto compute = [&](int u, const float* R0, const float* R1) {
        const float* wrow = wgt + u * KW;   // wave-uniform -> s_load
#pragma unroll
        for (int v = 0; v < KW; ++v) {
            const float wv = wrow[v];
#pragma unroll
            for (int c = 0; c < 8; ++c) {
                acc0[c] = fmaf(R0[v + c], wv, acc0[c]);
                acc1[c] = fmaf(R1[v + c], wv, acc1[c]);
            }
        }
    };

    load_win(A, or0);                 // W(0)
#pragma unroll 1
    for (int uu = 0; uu < KH; uu += 2) {
        load_win(B, or0 + uu + 1);    // W(uu+1)
        compute(uu, A, B);            // rows W(uu), W(uu+1)
        load_win(A, or0 + uu + 2);    // W(uu+2)  (max row 78, staged)
        compute(uu + 1, B, A);        // rows W(uu+1), W(uu+2)
    }

    // ---- store (guarded, scalar for edge correctness) ----
    const float bv = bias[0];
#pragma unroll
    for (int r = 0; r < 2; ++r) {
        const int i = gy0 + or0 + r;
        if (i < OH) {
            float* orow = out + (size_t)i * OW;
            const float* acc = r ? acc1 : acc0;
#pragma unroll
            for (int c = 0; c < 8; ++c) {
                const int j = gx0 + tx * 8 + c;
                if (j < OW) orow[j] = acc[c] + bv;
            }
        }
    }
}

extern "C" void kernel_launch(void* const* d_in, const int* in_sizes, int n_in,
                              void* d_out, int out_size, void* d_ws, size_t ws_size,
                              hipStream_t stream) {
    const float* x  = (const float*)d_in[0];
    const float* w  = (const float*)d_in[1];
    const float* b  = (const float*)d_in[2];
    float* out = (float*)d_out;
    dim3 grid((OW + TILE - 1) / TILE, (OH + TILE - 1) / TILE);
    conv16_kernel<<<grid, dim3(256), 0, stream>>>(x, w, b, out);
}

// Round 2
// 135.489 us; speedup vs baseline: 1.4747x; 1.4747x over previous
//
#include <hip/hip_runtime.h>

#define IH 4096
#define IW 4096
#define KH 16
#define KW 16
#define OH 4081
#define OW 4081

#define TBR 64      // output rows per block
#define TBC 128     // output cols per block
#define LROWS 79    // TBR + 15
#define LSTR 192    // bf16 per x-tile LDS row (24 chunks of 8; xor-swizzle closed)
#define BSTR 40     // bf16 per B-table LDS row (padded vs 32 for bank spread)

typedef short bf16x8 __attribute__((ext_vector_type(8)));
typedef float f32x4  __attribute__((ext_vector_type(4)));

static __device__ __forceinline__ unsigned int f2bf(float f) {
    unsigned int u = __float_as_uint(f);
    return (u + 0x7FFFu + ((u >> 16) & 1u)) >> 16;   // RTNE
}

// ---- pre-kernel: B[k=(u,v')][n] = w[u][v'-n] (0 outside band), bf16 ----
// ws layout: idx = u*512 + n*32 + v'   (16 KB)
__global__ void build_B(const float* __restrict__ wgt, unsigned short* __restrict__ Btab) {
    int idx = blockIdx.x * 256 + threadIdx.x;      // 0..8191
    if (idx >= 16 * 16 * 32) return;
    int vp = idx & 31;
    int n  = (idx >> 5) & 15;
    int u  = idx >> 9;
    int t  = vp - n;
    float val = (t >= 0 && t < KW) ? wgt[u * KW + t] : 0.0f;
    Btab[idx] = (unsigned short)f2bf(val);
}

__global__ __launch_bounds__(512, 4)
void conv_mfma(const float* __restrict__ x,
               const unsigned short* __restrict__ Btab,
               const float* __restrict__ bias,
               float* __restrict__ out) {
    __shared__ unsigned short tile[LROWS * LSTR];   // 29.6 KB x-tile (bf16)
    __shared__ unsigned short ldsB[16 * 16 * BSTR]; // 20 KB shifted-weight table

    const int tid  = threadIdx.x;
    const int lane = tid & 63;
    const int wv   = tid >> 6;        // 0..7
    const int n    = lane & 15;       // A row m / B col n / C col
    const int q4   = lane >> 4;       // quad 0..3
    const int gy0  = blockIdx.y * TBR;
    const int gx0  = blockIdx.x * TBC;

    // ---- stage x tile: 79 rows x 144 cols fp32 -> bf16 LDS, chunk-xor swizzle ----
    for (int idx = tid; idx < LROWS * 36; idx += 512) {
        int row = idx / 36;
        int c   = idx - row * 36;      // float4 index, col = 4c
        int gy  = gy0 + row;
        int gx  = gx0 + 4 * c;
        float4 q = make_float4(0.f, 0.f, 0.f, 0.f);
        if (gy < IH) {
            if (gx + 4 <= IW) {
                q = *reinterpret_cast<const float4*>(x + (size_t)gy * IW + gx);
            } else {
                float e0 = (gx + 0 < IW) ? x[(size_t)gy * IW + gx + 0] : 0.f;
                float e1 = (gx + 1 < IW) ? x[(size_t)gy * IW + gx + 1] : 0.f;
                float e2 = (gx + 2 < IW) ? x[(size_t)gy * IW + gx + 2] : 0.f;
                float e3 = (gx + 3 < IW) ? x[(size_t)gy * IW + gx + 3] : 0.f;
                q = make_float4(e0, e1, e2, e3);
            }
        }
        uint2 packed;
        packed.x = f2bf(q.x) | (f2bf(q.y) << 16);
        packed.y = f2bf(q.z) | (f2bf(q.w) << 16);
        int chunk = c >> 1;
        int half  = c & 1;
        int phys  = chunk ^ (row & 7);
        *reinterpret_cast<uint2*>(&tile[row * LSTR + phys * 8 + half * 4]) = packed;
    }

    // ---- stage B table into padded LDS ----
    for (int idx = tid; idx < 16 * 16 * 32; idx += 512) {
        int vp = idx & 31;
        int un = idx >> 5;            // u*16+n
        ldsB[un * BSTR + vp] = Btab[idx];
    }
    __syncthreads();

    // ---- MFMA main: wave = 1 row-block x 4 col-blocks of 16x16 C-tiles ----
    const int rb  = wv >> 1;          // 0..3
    const int cg  = wv & 1;           // 0..1
    const int li0 = rb * 16;

    f32x4 acc0 = {0.f, 0.f, 0.f, 0.f};
    f32x4 acc1 = {0.f, 0.f, 0.f, 0.f};
    f32x4 acc2 = {0.f, 0.f, 0.f, 0.f};
    f32x4 acc3 = {0.f, 0.f, 0.f, 0.f};

    const int cbase = cg * 8 + q4;    // + 2t, then ^ (row&7)

#pragma unroll
    for (int u = 0; u < KH; ++u) {
        bf16x8 bf = *reinterpret_cast<const bf16x8*>(&ldsB[(u * 16 + n) * BSTR + q4 * 8]);
        int row = li0 + n + u;
        int swz = row & 7;
        const unsigned short* rbase = &tile[row * LSTR];
        bf16x8 a0 = *reinterpret_cast<const bf16x8*>(rbase + ((cbase + 0) ^ swz) * 8);
        bf16x8 a1 = *reinterpret_cast<const bf16x8*>(rbase + ((cbase + 2) ^ swz) * 8);
        bf16x8 a2 = *reinterpret_cast<const bf16x8*>(rbase + ((cbase + 4) ^ swz) * 8);
        bf16x8 a3 = *reinterpret_cast<const bf16x8*>(rbase + ((cbase + 6) ^ swz) * 8);
        acc0 = __builtin_amdgcn_mfma_f32_16x16x32_bf16(a0, bf, acc0, 0, 0, 0);
        acc1 = __builtin_amdgcn_mfma_f32_16x16x32_bf16(a1, bf, acc1, 0, 0, 0);
        acc2 = __builtin_amdgcn_mfma_f32_16x16x32_bf16(a2, bf, acc2, 0, 0, 0);
        acc3 = __builtin_amdgcn_mfma_f32_16x16x32_bf16(a3, bf, acc3, 0, 0, 0);
    }

    // ---- epilogue: C/D layout col=lane&15, row=quad*4+reg ----
    const float bv = bias[0];
    const int orow0 = gy0 + li0 + q4 * 4;
    const int ocol0 = gx0 + cg * 64 + n;

#pragma unroll
    for (int t = 0; t < 4; ++t) {
        const f32x4 acc = (t == 0) ? acc0 : (t == 1) ? acc1 : (t == 2) ? acc2 : acc3;
        int col = ocol0 + t * 16;
        if (col < OW) {
#pragma unroll
            for (int r = 0; r < 4; ++r) {
                int rr = orow0 + r;
                if (rr < OH) out[(size_t)rr * OW + col] = acc[r] + bv;
            }
        }
    }
}

extern "C" void kernel_launch(void* const* d_in, const int* in_sizes, int n_in,
                              void* d_out, int out_size, void* d_ws, size_t ws_size,
                              hipStream_t stream) {
    const float* x  = (const float*)d_in[0];
    const float* w  = (const float*)d_in[1];
    const float* b  = (const float*)d_in[2];
    float* out = (float*)d_out;
    unsigned short* Btab = (unsigned short*)d_ws;

    build_B<<<32, 256, 0, stream>>>(w, Btab);

    dim3 grid((OW + TBC - 1) / TBC, (OH + TBR - 1) / TBR);  // 32 x 64
    conv_mfma<<<grid, dim3(512), 0, stream>>>(x, Btab, b, out);
}